// Round 5
// baseline (69.044 us; speedup 1.0000x reference)
//
#include <hip/hip_runtime.h>
#include <hip/hip_bf16.h>

typedef __attribute__((ext_vector_type(8))) short bf16x8;
typedef __attribute__((ext_vector_type(4))) float f32x4;

__device__ __forceinline__ unsigned short f2bf(float f) {
    union { float f; unsigned int u; } v; v.f = f;
    unsigned int u = v.u;
    unsigned int r = u + 0x7FFFu + ((u >> 16) & 1u);   // RNE
    return (unsigned short)(r >> 16);
}

#define GLDS16(gsrc, ldst)                                                          \
    __builtin_amdgcn_global_load_lds(                                               \
        (const __attribute__((address_space(1))) unsigned int*)(gsrc),              \
        (__attribute__((address_space(3))) unsigned int*)(ldst), 16, 0, 0)

// ---------------- kernel 0: W transpose+convert -> Wt[192][384] bf16 ----------------
__global__ __launch_bounds__(256) void wprep(const float* __restrict__ Wq,
                                             const float* __restrict__ Wk,
                                             const float* __restrict__ Wv,
                                             unsigned short* __restrict__ Wt) {
    int idx = blockIdx.x * 256 + threadIdx.x;          // 3*64*384 = 73728
    if (idx >= 3 * 64 * 384) return;
    int w   = idx / (64 * 384);
    int rem = idx % (64 * 384);
    int n = rem / 384, k = rem % 384;
    const float* W = (w == 0) ? Wq : ((w == 1) ? Wk : Wv);
    Wt[idx] = f2bf(W[k * 64 + n]);
}

// ---------------- kernel 1: qkv = x @ [Wq|Wk|Wv] — streaming, no K-loop barriers ----
// B (Wt, 192x384 bf16 = 147456B) staged ONCE into LDS per block (glds, source-side
// chunk-XOR swizzle, linear dest; read with same XOR -> <=2-way conflicts = free).
// A streams from global into a 2-deep register double buffer per wave, anchored by
// asm vmcnt + sched_barrier fences; 16KB/wave stays in flight across the whole
// compute phase. One barrier total. 4 waves (2x2), wave tile 64x96, grid 256,
// rt-loop covers 2 row-tiles of 128 so B is staged once per CU.
template<int S>
__device__ __forceinline__ void qstep(const float* __restrict__ xw,
                                      const unsigned short* __restrict__ B_lds,
                                      float4 (&cur)[8],
                                      f32x4 (&acc)[4][6],
                                      int wc, int l15, int lg) {
    if (S < 11) { asm volatile("s_waitcnt vmcnt(8)" ::: "memory"); }
    else        { asm volatile("s_waitcnt vmcnt(0)" ::: "memory"); }
    __builtin_amdgcn_sched_barrier(0);
    // convert landed A chunk -> fragments
    bf16x8 afr[4];
#pragma unroll
    for (int m = 0; m < 4; ++m) {
        afr[m][0] = (short)f2bf(cur[m * 2].x);     afr[m][1] = (short)f2bf(cur[m * 2].y);
        afr[m][2] = (short)f2bf(cur[m * 2].z);     afr[m][3] = (short)f2bf(cur[m * 2].w);
        afr[m][4] = (short)f2bf(cur[m * 2 + 1].x); afr[m][5] = (short)f2bf(cur[m * 2 + 1].y);
        afr[m][6] = (short)f2bf(cur[m * 2 + 1].z); afr[m][7] = (short)f2bf(cur[m * 2 + 1].w);
    }
    // refill this buffer with chunk S+2 (stays in flight across next step's compute)
    if (S + 2 < 12) {
#pragma unroll
        for (int m = 0; m < 4; ++m) {
            cur[m * 2 + 0] = *reinterpret_cast<const float4*>(xw + (size_t)m * 16 * 384 + (S + 2) * 32);
            cur[m * 2 + 1] = *reinterpret_cast<const float4*>(xw + (size_t)m * 16 * 384 + (S + 2) * 32 + 4);
        }
    }
    __builtin_amdgcn_sched_barrier(0);
    // B fragments from LDS (swizzled) + 24 MFMA
    bf16x8 bfr[6];
#pragma unroll
    for (int n = 0; n < 6; ++n) {
        int col  = wc * 96 + n * 16 + l15;
        int byte = col * 768 + (((S * 4 + lg) ^ (col & 7)) << 4);
        bfr[n] = *reinterpret_cast<const bf16x8*>(reinterpret_cast<const char*>(B_lds) + byte);
    }
#pragma unroll
    for (int m = 0; m < 4; ++m)
#pragma unroll
        for (int n = 0; n < 6; ++n)
            acc[m][n] = __builtin_amdgcn_mfma_f32_16x16x32_bf16(afr[m], bfr[n], acc[m][n], 0, 0, 0);
}

__global__ __launch_bounds__(256) void qkv_gemm(const float* __restrict__ x,
                                                const unsigned short* __restrict__ Wt,
                                                unsigned short* __restrict__ q_ws,
                                                unsigned short* __restrict__ k_ws,
                                                unsigned short* __restrict__ vt_ws) {
    __shared__ __align__(16) unsigned short B_lds[192 * 384];   // 147456 B

    const int tid  = threadIdx.x;
    const int lane = tid & 63;
    const int wid  = tid >> 6;
    const int wr = wid >> 1, wc = wid & 1;
    const int l15 = lane & 15, lg = lane >> 4;

    // ---- stage B once: 144 glds wave-instrs (36 per wave), source-XOR swizzled ----
#pragma unroll
    for (int i = 0; i < 36; ++i) {
        int n    = wid * 36 + i;
        int L    = n * 1024 + lane * 16;      // target LDS byte
        int col  = L / 768;                   // 0..191
        int phys = (L % 768) >> 4;            // 0..47 (16B chunk within col)
        int lgc  = phys ^ (col & 7);          // logical chunk at this phys slot
        GLDS16(Wt + (size_t)col * 384 + lgc * 8, (char*)B_lds + n * 1024);
    }

    for (int rt = 0; rt < 2; ++rt) {
        const int row0 = blockIdx.x * 256 + rt * 128;
        const float* xw = x + (size_t)(row0 + wr * 64 + l15) * 384 + lg * 8;

        // prologue: chunks 0 and 1 into the two named buffers
        float4 aA[8], aB[8];
#pragma unroll
        for (int m = 0; m < 4; ++m) {
            aA[m * 2 + 0] = *reinterpret_cast<const float4*>(xw + (size_t)m * 16 * 384 + 0);
            aA[m * 2 + 1] = *reinterpret_cast<const float4*>(xw + (size_t)m * 16 * 384 + 4);
        }
#pragma unroll
        for (int m = 0; m < 4; ++m) {
            aB[m * 2 + 0] = *reinterpret_cast<const float4*>(xw + (size_t)m * 16 * 384 + 32);
            aB[m * 2 + 1] = *reinterpret_cast<const float4*>(xw + (size_t)m * 16 * 384 + 36);
        }
        __builtin_amdgcn_sched_barrier(0);
        if (rt == 0) {
            asm volatile("s_waitcnt vmcnt(16)" ::: "memory");   // all glds landed; 16 A loads in flight
            __builtin_amdgcn_s_barrier();                       // B_lds visible to all waves
        }

        f32x4 acc[4][6] = {};
        qstep<0>(xw, B_lds, aA, acc, wc, l15, lg);
        qstep<1>(xw, B_lds, aB, acc, wc, l15, lg);
        qstep<2>(xw, B_lds, aA, acc, wc, l15, lg);
        qstep<3>(xw, B_lds, aB, acc, wc, l15, lg);
        qstep<4>(xw, B_lds, aA, acc, wc, l15, lg);
        qstep<5>(xw, B_lds, aB, acc, wc, l15, lg);
        qstep<6>(xw, B_lds, aA, acc, wc, l15, lg);
        qstep<7>(xw, B_lds, aB, acc, wc, l15, lg);
        qstep<8>(xw, B_lds, aA, acc, wc, l15, lg);
        qstep<9>(xw, B_lds, aB, acc, wc, l15, lg);
        qstep<10>(xw, B_lds, aA, acc, wc, l15, lg);
        qstep<11>(xw, B_lds, aB, acc, wc, l15, lg);

        // ---- epilogue: C/D layout col=lane&15, row=(lane>>4)*4+j ----
#pragma unroll
        for (int m = 0; m < 4; ++m) {
#pragma unroll
            for (int n = 0; n < 6; ++n) {
                int colb = wc * 96 + n * 16 + l15;
#pragma unroll
                for (int j = 0; j < 4; ++j) {
                    int row = row0 + wr * 64 + m * 16 + lg * 4 + j;
                    unsigned short hv = f2bf(acc[m][n][j]);
                    if (colb < 64) {
                        q_ws[(size_t)row * 64 + colb] = hv;
                    } else if (colb < 128) {
                        k_ws[(size_t)row * 64 + (colb - 64)] = hv;
                    } else {
                        int bb = row >> 8, t = row & 255, h = colb - 128;
                        vt_ws[((size_t)bb * 64 + h) * 256 + t] = hv;   // v stored transposed
                    }
                }
            }
        }
    }
}

// ---------------- kernel 2: causal flash attention, one block per batch ----------------
__global__ __launch_bounds__(256, 1) void attn(const unsigned short* __restrict__ q_ws,
                                               const unsigned short* __restrict__ k_ws,
                                               const unsigned short* __restrict__ vt_ws,
                                               float* __restrict__ out) {
    __shared__ unsigned short P_lds[4][64][72];   // per-wave P staging, padded

    const int b = blockIdx.x;
    const int tid = threadIdx.x, lane = tid & 63, w = tid >> 6;
    const int l15 = lane & 15, lg = lane >> 4;
    const unsigned short* qb = q_ws + (size_t)b * 256 * 64;
    const unsigned short* kb = k_ws + (size_t)b * 256 * 64;
    const unsigned short* vb = vt_ws + (size_t)b * 64 * 256;
    float* ob = out + (size_t)b * 256 * 64;
    const int r0 = w * 64;
    const float scale = 0.05103103630798287f;     // 384^-0.5

    f32x4 o[4][4] = {};
    float M[4][4], L[4][4];
#pragma unroll
    for (int m = 0; m < 4; ++m)
#pragma unroll
        for (int j = 0; j < 4; ++j) { M[m][j] = -1e30f; L[m][j] = 0.f; }

    for (int jt = 0; jt <= w; ++jt) {
        // ---- S = q @ K^T for this 64-col tile ----
        f32x4 s[4][4] = {};
#pragma unroll
        for (int kk = 0; kk < 2; ++kk) {
            bf16x8 aq[4], bk[4];
#pragma unroll
            for (int m = 0; m < 4; ++m)
                aq[m] = *reinterpret_cast<const bf16x8*>(qb + (size_t)(r0 + m * 16 + l15) * 64 + kk * 32 + lg * 8);
#pragma unroll
            for (int n = 0; n < 4; ++n)
                bk[n] = *reinterpret_cast<const bf16x8*>(kb + (size_t)(jt * 64 + n * 16 + l15) * 64 + kk * 32 + lg * 8);
#pragma unroll
            for (int m = 0; m < 4; ++m)
#pragma unroll
                for (int n = 0; n < 4; ++n)
                    s[m][n] = __builtin_amdgcn_mfma_f32_16x16x32_bf16(aq[m], bk[n], s[m][n], 0, 0, 0);
        }
        // ---- scale + causal mask + tile row-max ----
        float tm[4][4];
#pragma unroll
        for (int m = 0; m < 4; ++m)
#pragma unroll
            for (int j = 0; j < 4; ++j) tm[m][j] = -1e30f;
#pragma unroll
        for (int m = 0; m < 4; ++m) {
#pragma unroll
            for (int n = 0; n < 4; ++n) {
                int colg = jt * 64 + n * 16 + l15;
#pragma unroll
                for (int j = 0; j < 4; ++j) {
                    int rowg = r0 + m * 16 + lg * 4 + j;
                    float v = s[m][n][j] * scale;
                    if (colg > rowg) v = -1e30f;
                    s[m][n][j] = v;
                    tm[m][j] = fmaxf(tm[m][j], v);
                }
            }
        }
#pragma unroll
        for (int m = 0; m < 4; ++m)
#pragma unroll
            for (int j = 0; j < 4; ++j) {
                float v = tm[m][j];
                v = fmaxf(v, __shfl_xor(v, 1));
                v = fmaxf(v, __shfl_xor(v, 2));
                v = fmaxf(v, __shfl_xor(v, 4));
                v = fmaxf(v, __shfl_xor(v, 8));
                tm[m][j] = v;
            }
        float alpha[4][4];
#pragma unroll
        for (int m = 0; m < 4; ++m)
#pragma unroll
            for (int j = 0; j < 4; ++j) {
                float mn = fmaxf(M[m][j], tm[m][j]);
                alpha[m][j] = __expf(M[m][j] - mn);
                M[m][j] = mn;
            }
        // ---- P = exp(S - M), tile row-sum ----
        float ts[4][4] = {};
#pragma unroll
        for (int m = 0; m < 4; ++m)
#pragma unroll
            for (int n = 0; n < 4; ++n)
#pragma unroll
                for (int j = 0; j < 4; ++j) {
                    float p = __expf(s[m][n][j] - M[m][j]);
                    s[m][n][j] = p;
                    ts[m][j] += p;
                }
#pragma unroll
        for (int m = 0; m < 4; ++m)
#pragma unroll
            for (int j = 0; j < 4; ++j) {
                float v = ts[m][j];
                v += __shfl_xor(v, 1);
                v += __shfl_xor(v, 2);
                v += __shfl_xor(v, 4);
                v += __shfl_xor(v, 8);
                L[m][j] = L[m][j] * alpha[m][j] + v;
            }
        // ---- rescale O ----
#pragma unroll
        for (int m = 0; m < 4; ++m)
#pragma unroll
            for (int n = 0; n < 4; ++n)
#pragma unroll
                for (int j = 0; j < 4; ++j) o[m][n][j] *= alpha[m][j];
        // ---- P -> LDS (bf16) for A-operand restage ----
#pragma unroll
        for (int m = 0; m < 4; ++m)
#pragma unroll
            for (int n = 0; n < 4; ++n)
#pragma unroll
                for (int j = 0; j < 4; ++j)
                    P_lds[w][m * 16 + lg * 4 + j][n * 16 + l15] = f2bf(s[m][n][j]);
        asm volatile("s_waitcnt lgkmcnt(0)" ::: "memory");   // wave-internal LDS RAW fence
        // ---- O += P @ V  (V transposed in global: vb[h][t]) ----
#pragma unroll
        for (int kk = 0; kk < 2; ++kk) {
            bf16x8 ap[4], bv[4];
#pragma unroll
            for (int m = 0; m < 4; ++m)
                ap[m] = *reinterpret_cast<const bf16x8*>(&P_lds[w][m * 16 + l15][kk * 32 + lg * 8]);
#pragma unroll
            for (int n = 0; n < 4; ++n)
                bv[n] = *reinterpret_cast<const bf16x8*>(vb + (size_t)(n * 16 + l15) * 256 + jt * 64 + kk * 32 + lg * 8);
#pragma unroll
            for (int m = 0; m < 4; ++m)
#pragma unroll
                for (int n = 0; n < 4; ++n)
                    o[m][n] = __builtin_amdgcn_mfma_f32_16x16x32_bf16(ap[m], bv[n], o[m][n], 0, 0, 0);
        }
    }
    // ---- normalize + store fp32 ----
#pragma unroll
    for (int m = 0; m < 4; ++m) {
#pragma unroll
        for (int n = 0; n < 4; ++n) {
            int h = n * 16 + l15;
#pragma unroll
            for (int j = 0; j < 4; ++j) {
                int t = r0 + m * 16 + lg * 4 + j;
                ob[(size_t)t * 64 + h] = o[m][n][j] / L[m][j];
            }
        }
    }
}

extern "C" void kernel_launch(void* const* d_in, const int* in_sizes, int n_in,
                              void* d_out, int out_size, void* d_ws, size_t ws_size,
                              hipStream_t stream) {
    const float* x  = (const float*)d_in[0];
    const float* Wq = (const float*)d_in[1];
    const float* Wk = (const float*)d_in[2];
    const float* Wv = (const float*)d_in[3];
    float* out = (float*)d_out;

    char* ws = (char*)d_ws;
    unsigned short* q_ws  = (unsigned short*)(ws);                 // [65536][64] bf16
    unsigned short* k_ws  = (unsigned short*)(ws + 8388608);       // [65536][64] bf16
    unsigned short* vt_ws = (unsigned short*)(ws + 16777216);      // [256][64][256] bf16 (v^T)
    unsigned short* Wt    = (unsigned short*)(ws + 25165824);      // [192][384] bf16

    wprep<<<288, 256, 0, stream>>>(Wq, Wk, Wv, Wt);
    qkv_gemm<<<256, 256, 0, stream>>>(x, Wt, q_ws, k_ws, vt_ws);
    attn<<<256, 256, 0, stream>>>(q_ws, k_ws, vt_ws, out);
}

// Round 6
// 53.326 us; speedup vs baseline: 1.2948x; 1.2948x over previous
//
#include <hip/hip_runtime.h>
#include <hip/hip_bf16.h>

typedef __attribute__((ext_vector_type(8))) short bf16x8;
typedef __attribute__((ext_vector_type(4))) float f32x4;

__device__ __forceinline__ unsigned short f2bf(float f) {
    union { float f; unsigned int u; } v; v.f = f;
    unsigned int u = v.u;
    unsigned int r = u + 0x7FFFu + ((u >> 16) & 1u);   // RNE
    return (unsigned short)(r >> 16);
}

#define GLDS16(gsrc, ldst)                                                          \
    __builtin_amdgcn_global_load_lds(                                               \
        (const __attribute__((address_space(1))) unsigned int*)(gsrc),              \
        (__attribute__((address_space(3))) unsigned int*)(ldst), 16, 0, 0)

// ---------------- kernel 0: W -> Wt2, glds-linear GEMM-B layout ----------------
// Wt2[slab c=k/32][kc2=(k%32)/8][col 0..191][e=k%7] bf16; slab = 6144 shorts.
// A 12KB slab per K-chunk is a LINEAR copy into LDS [kc2][col][8] whose
// ds_read_b128 fragments (byte = kc2*3072 + col*16) are conflict-free.
__global__ __launch_bounds__(256) void wprep(const float* __restrict__ Wq,
                                             const float* __restrict__ Wk,
                                             const float* __restrict__ Wv,
                                             unsigned short* __restrict__ Wt2) {
    int idx = blockIdx.x * 256 + threadIdx.x;          // 3*64*384 = 73728
    if (idx >= 3 * 64 * 384) return;
    int w   = idx / (64 * 384);
    int rem = idx % (64 * 384);
    int n = rem / 384, k = rem % 384;
    const float* W = (w == 0) ? Wq : ((w == 1) ? Wk : Wv);
    int col = w * 64 + n;
    Wt2[(size_t)(k >> 5) * 6144 + ((k >> 3) & 3) * 1536 + col * 8 + (k & 7)] = f2bf(W[k * 64 + n]);
}

// ---------------- fused kernel: one block per batch ----------------
// Phase 1: Y[256][192] = x_b @ W (K=384, 12 chunks of 32). x via global_load_lds
//   fp32 (source-XOR chunk swizzle per row, matching swizzled reads), B via
//   linear glds of Wt2 slabs. Counted vmcnt(11), 2-deep prefetch, 2 barriers/chunk.
//   Wave w owns rows w*64..w*64+64, all 192 cols: acc[4][12].
// Phase 2: write q,k,v^T (bf16) to LDS, then causal flash attention from LDS.
#define XB0   0
#define XB1   32768
#define BB0   65536
#define BB1   77824
#define QOFF  0
#define KOFF  36864
#define VTOFF 73728
#define POFF  107520

__global__ __launch_bounds__(256, 1) void fused(const float* __restrict__ x,
                                                const unsigned short* __restrict__ Wt2,
                                                float* __restrict__ out) {
    __shared__ __align__(16) char smem[144384];

    const int b = blockIdx.x;
    const int tid = threadIdx.x, lane = tid & 63, w = tid >> 6;
    const int l15 = lane & 15, lg = lane >> 4;
    const float* xb = x + (size_t)b * 256 * 384;
    float* ob = out + (size_t)b * 256 * 64;

    const int xrow8 = lane >> 3;   // row within an 8-row glds group
    const int xphys = lane & 7;    // physical 16B chunk this lane fills

    // ---------------- phase 1: QKV GEMM ----------------
    auto issue = [&](int c) {
        char* xd = smem + ((c & 1) ? XB1 : XB0);
        char* bd = smem + ((c & 1) ? BB1 : BB0);
#pragma unroll
        for (int g = 0; g < 8; ++g) {                    // x: 8 glds/wave, 8 rows each
            int gg = w * 8 + g;
            int row = gg * 8 + xrow8;
            int lchunk = xphys ^ (row & 7);              // source-side XOR swizzle
            GLDS16(xb + (size_t)row * 384 + c * 32 + lchunk * 4, xd + gg * 1024);
        }
#pragma unroll
        for (int i = 0; i < 3; ++i) {                    // B: linear slab copy, 3/wave
            int h = w * 3 + i;
            GLDS16(Wt2 + (size_t)c * 6144 + h * 512 + lane * 8, bd + h * 1024);
        }
    };

    f32x4 acc[4][12] = {};

    issue(0);
    issue(1);
    for (int c = 0; c < 12; ++c) {
        if (c < 11) { asm volatile("s_waitcnt vmcnt(11)" ::: "memory"); }
        else        { asm volatile("s_waitcnt vmcnt(0)"  ::: "memory"); }
        __builtin_amdgcn_s_barrier();                    // buf(c) visible to all waves

        const char* xs = smem + ((c & 1) ? XB1 : XB0);
        const char* bs = smem + ((c & 1) ? BB1 : BB0);
        bf16x8 bfr[12];
#pragma unroll
        for (int n = 0; n < 12; ++n)
            bfr[n] = *reinterpret_cast<const bf16x8*>(bs + lg * 3072 + (n * 16 + l15) * 16);
        bf16x8 afr[4];
#pragma unroll
        for (int m = 0; m < 4; ++m) {
            int r = w * 64 + m * 16 + l15;
            int s0 = (2 * lg) ^ (r & 7), s1 = (2 * lg + 1) ^ (r & 7);
            float4 f0 = *reinterpret_cast<const float4*>(xs + r * 128 + s0 * 16);
            float4 f1 = *reinterpret_cast<const float4*>(xs + r * 128 + s1 * 16);
            afr[m][0] = (short)f2bf(f0.x); afr[m][1] = (short)f2bf(f0.y);
            afr[m][2] = (short)f2bf(f0.z); afr[m][3] = (short)f2bf(f0.w);
            afr[m][4] = (short)f2bf(f1.x); afr[m][5] = (short)f2bf(f1.y);
            afr[m][6] = (short)f2bf(f1.z); afr[m][7] = (short)f2bf(f1.w);
        }
#pragma unroll
        for (int m = 0; m < 4; ++m)
#pragma unroll
            for (int n = 0; n < 12; ++n)
                acc[m][n] = __builtin_amdgcn_mfma_f32_16x16x32_bf16(afr[m], bfr[n], acc[m][n], 0, 0, 0);

        __builtin_amdgcn_s_barrier();                    // all waves done with buf(c)
        if (c < 10) issue(c + 2);                        // refill buf(c) parity slot
    }

    // ---------------- stage q/k/v^T to LDS (C/D layout: col=l15, row=lg*4+j) ----
#pragma unroll
    for (int m = 0; m < 4; ++m) {
#pragma unroll
        for (int n = 0; n < 12; ++n) {
            int col = n * 16 + l15;
#pragma unroll
            for (int j = 0; j < 4; ++j) {
                int t = w * 64 + m * 16 + lg * 4 + j;
                unsigned short hv = f2bf(acc[m][n][j]);
                if (n < 4)
                    *reinterpret_cast<unsigned short*>(smem + QOFF + (t * 72 + col) * 2) = hv;
                else if (n < 8)
                    *reinterpret_cast<unsigned short*>(smem + KOFF + (t * 72 + (col - 64)) * 2) = hv;
                else
                    *reinterpret_cast<unsigned short*>(smem + VTOFF + ((col - 128) * 264 + t) * 2) = hv;
            }
        }
    }
    __syncthreads();

    // ---------------- phase 2: causal flash attention from LDS ----------------
    char* Pw = smem + POFF + w * 9216;                   // per-wave P[64][72]
    const int r0 = w * 64;
    const float scale = 0.05103103630798287f;            // 384^-0.5

    f32x4 o[4][4] = {};
    float M[4][4], L[4][4];
#pragma unroll
    for (int m = 0; m < 4; ++m)
#pragma unroll
        for (int j = 0; j < 4; ++j) { M[m][j] = -1e30f; L[m][j] = 0.f; }

    for (int jt = 0; jt <= w; ++jt) {
        // ---- S = q @ K^T ----
        f32x4 s[4][4] = {};
#pragma unroll
        for (int kk = 0; kk < 2; ++kk) {
            bf16x8 aq[4], bk[4];
#pragma unroll
            for (int m = 0; m < 4; ++m)
                aq[m] = *reinterpret_cast<const bf16x8*>(smem + QOFF + ((r0 + m * 16 + l15) * 72 + kk * 32 + lg * 8) * 2);
#pragma unroll
            for (int n = 0; n < 4; ++n)
                bk[n] = *reinterpret_cast<const bf16x8*>(smem + KOFF + ((jt * 64 + n * 16 + l15) * 72 + kk * 32 + lg * 8) * 2);
#pragma unroll
            for (int m = 0; m < 4; ++m)
#pragma unroll
                for (int n = 0; n < 4; ++n)
                    s[m][n] = __builtin_amdgcn_mfma_f32_16x16x32_bf16(aq[m], bk[n], s[m][n], 0, 0, 0);
        }
        // ---- scale + causal mask + tile row-max ----
        float tm[4][4];
#pragma unroll
        for (int m = 0; m < 4; ++m)
#pragma unroll
            for (int j = 0; j < 4; ++j) tm[m][j] = -1e30f;
#pragma unroll
        for (int m = 0; m < 4; ++m) {
#pragma unroll
            for (int n = 0; n < 4; ++n) {
                int colg = jt * 64 + n * 16 + l15;
#pragma unroll
                for (int j = 0; j < 4; ++j) {
                    int rowg = r0 + m * 16 + lg * 4 + j;
                    float v = s[m][n][j] * scale;
                    if (colg > rowg) v = -1e30f;
                    s[m][n][j] = v;
                    tm[m][j] = fmaxf(tm[m][j], v);
                }
            }
        }
#pragma unroll
        for (int m = 0; m < 4; ++m)
#pragma unroll
            for (int j = 0; j < 4; ++j) {
                float v = tm[m][j];
                v = fmaxf(v, __shfl_xor(v, 1));
                v = fmaxf(v, __shfl_xor(v, 2));
                v = fmaxf(v, __shfl_xor(v, 4));
                v = fmaxf(v, __shfl_xor(v, 8));
                tm[m][j] = v;
            }
        float alpha[4][4];
#pragma unroll
        for (int m = 0; m < 4; ++m)
#pragma unroll
            for (int j = 0; j < 4; ++j) {
                float mn = fmaxf(M[m][j], tm[m][j]);
                alpha[m][j] = __expf(M[m][j] - mn);
                M[m][j] = mn;
            }
        // ---- P = exp(S - M), tile row-sum ----
        float ts[4][4] = {};
#pragma unroll
        for (int m = 0; m < 4; ++m)
#pragma unroll
            for (int n = 0; n < 4; ++n)
#pragma unroll
                for (int j = 0; j < 4; ++j) {
                    float p = __expf(s[m][n][j] - M[m][j]);
                    s[m][n][j] = p;
                    ts[m][j] += p;
                }
#pragma unroll
        for (int m = 0; m < 4; ++m)
#pragma unroll
            for (int j = 0; j < 4; ++j) {
                float v = ts[m][j];
                v += __shfl_xor(v, 1);
                v += __shfl_xor(v, 2);
                v += __shfl_xor(v, 4);
                v += __shfl_xor(v, 8);
                L[m][j] = L[m][j] * alpha[m][j] + v;
            }
        // ---- rescale O ----
#pragma unroll
        for (int m = 0; m < 4; ++m)
#pragma unroll
            for (int n = 0; n < 4; ++n)
#pragma unroll
                for (int j = 0; j < 4; ++j) o[m][n][j] *= alpha[m][j];
        // ---- P -> per-wave LDS (bf16) ----
#pragma unroll
        for (int m = 0; m < 4; ++m)
#pragma unroll
            for (int n = 0; n < 4; ++n)
#pragma unroll
                for (int j = 0; j < 4; ++j)
                    *reinterpret_cast<unsigned short*>(Pw + ((m * 16 + lg * 4 + j) * 72 + n * 16 + l15) * 2) = f2bf(s[m][n][j]);
        asm volatile("s_waitcnt lgkmcnt(0)" ::: "memory");   // wave-internal LDS RAW fence
        // ---- O += P @ V ----
#pragma unroll
        for (int kk = 0; kk < 2; ++kk) {
            bf16x8 ap[4], bv[4];
#pragma unroll
            for (int m = 0; m < 4; ++m)
                ap[m] = *reinterpret_cast<const bf16x8*>(Pw + ((m * 16 + l15) * 72 + kk * 32 + lg * 8) * 2);
#pragma unroll
            for (int n = 0; n < 4; ++n)
                bv[n] = *reinterpret_cast<const bf16x8*>(smem + VTOFF + ((n * 16 + l15) * 264 + jt * 64 + kk * 32 + lg * 8) * 2);
#pragma unroll
            for (int m = 0; m < 4; ++m)
#pragma unroll
                for (int n = 0; n < 4; ++n)
                    o[m][n] = __builtin_amdgcn_mfma_f32_16x16x32_bf16(ap[m], bv[n], o[m][n], 0, 0, 0);
        }
    }
    // ---- normalize + store fp32 ----
#pragma unroll
    for (int m = 0; m < 4; ++m) {
#pragma unroll
        for (int n = 0; n < 4; ++n) {
            int h = n * 16 + l15;
#pragma unroll
            for (int j = 0; j < 4; ++j) {
                int t = r0 + m * 16 + lg * 4 + j;
                ob[(size_t)t * 64 + h] = o[m][n][j] / L[m][j];
            }
        }
    }
}

extern "C" void kernel_launch(void* const* d_in, const int* in_sizes, int n_in,
                              void* d_out, int out_size, void* d_ws, size_t ws_size,
                              hipStream_t stream) {
    const float* x  = (const float*)d_in[0];
    const float* Wq = (const float*)d_in[1];
    const float* Wk = (const float*)d_in[2];
    const float* Wv = (const float*)d_in[3];
    float* out = (float*)d_out;

    unsigned short* Wt2 = (unsigned short*)d_ws;   // [12 slabs][4][192][8] bf16 = 147456 B

    wprep<<<288, 256, 0, stream>>>(Wq, Wk, Wv, Wt2);
    fused<<<256, 256, 0, stream>>>(x, Wt2, out);
}

// Round 7
// 45.146 us; speedup vs baseline: 1.5293x; 1.1812x over previous
//
#include <hip/hip_runtime.h>
#include <hip/hip_bf16.h>

typedef __attribute__((ext_vector_type(8))) short bf16x8;
typedef __attribute__((ext_vector_type(4))) float f32x4;

__device__ __forceinline__ unsigned short f2bf(float f) {
    union { float f; unsigned int u; } v; v.f = f;
    unsigned int u = v.u;
    unsigned int r = u + 0x7FFFu + ((u >> 16) & 1u);   // RNE
    return (unsigned short)(r >> 16);
}

#define GLDS16(gsrc, ldst)                                                          \
    __builtin_amdgcn_global_load_lds(                                               \
        (const __attribute__((address_space(1))) unsigned int*)(gsrc),              \
        (__attribute__((address_space(3))) unsigned int*)(ldst), 16, 0, 0)

// ---------------- kernel 0: W -> Wt2 [c=12][kc2=4][col=192][8] bf16 ----------------
__global__ __launch_bounds__(256) void wprep(const float* __restrict__ Wq,
                                             const float* __restrict__ Wk,
                                             const float* __restrict__ Wv,
                                             unsigned short* __restrict__ Wt2) {
    int idx = blockIdx.x * 256 + threadIdx.x;          // 3*64*384 = 73728
    if (idx >= 73728) return;
    int w   = idx / 24576;
    int rem = idx % 24576;
    int n = rem / 384, k = rem % 384;
    const float* W = (w == 0) ? Wq : ((w == 1) ? Wk : Wv);
    int col = w * 64 + n;
    Wt2[(size_t)(k >> 5) * 6144 + ((k >> 3) & 3) * 1536 + col * 8 + (k & 7)] = f2bf(W[k * 64 + n]);
}

// ---------------- fused kernel: one block per batch, 512 threads / 8 waves ----------
#define XB0   0
#define XB1   32768
#define BB0   65536
#define BB1   77824
#define QOFF  0
#define KOFF  36864
#define VTOFF 73728
#define POFF  107520

__global__ __launch_bounds__(512, 2) void fused(const float* __restrict__ x,
                                                const unsigned short* __restrict__ Wt2,
                                                float* __restrict__ out) {
    __shared__ __align__(16) char smem[144384];

    const int b = blockIdx.x;
    const int tid = threadIdx.x, lane = tid & 63, wid = tid >> 6;
    const int l15 = lane & 15, lg = lane >> 4;
    const int wr = wid >> 1, wc = wid & 1;             // phase-1 wave grid 4x2
    const float* xb = x + (size_t)b * 98304;
    float* ob = out + (size_t)b * 16384;
    const int xrow8 = lane >> 3;                       // row within 8-row glds group
    const int xphys = lane & 7;                        // physical 16B chunk this lane fills

    // ---------------- phase 1: Y[256][192] = x_b @ W ----------------
    auto issue = [&](int c) {
        char* xd = smem + ((c & 1) ? XB1 : XB0);
        char* bd = smem + ((c & 1) ? BB1 : BB0);
#pragma unroll
        for (int g = 0; g < 4; ++g) {                  // x: 4 glds/wave (32 total, 32KB)
            int gg = wid * 4 + g;
            int row = gg * 8 + xrow8;
            int lchunk = xphys ^ (row & 7);            // source-side XOR swizzle
            GLDS16(xb + (size_t)row * 384 + c * 32 + lchunk * 4, xd + gg * 1024);
        }
        // B: 12KB = 12 glds; waves 0-3 take 2, waves 4-7 take 1
        if (wid < 4) {
            GLDS16(Wt2 + (size_t)c * 6144 + (wid * 2) * 512 + lane * 8, bd + (wid * 2) * 1024);
            GLDS16(Wt2 + (size_t)c * 6144 + (wid * 2 + 1) * 512 + lane * 8, bd + (wid * 2 + 1) * 1024);
        } else {
            GLDS16(Wt2 + (size_t)c * 6144 + (4 + wid) * 512 + lane * 8, bd + (4 + wid) * 1024);
        }
    };

    f32x4 acc[4][6] = {};
    issue(0);
    issue(1);
#pragma unroll
    for (int c = 0; c < 12; ++c) {
        if (c < 11) {                                  // wait chunk c (c+1 stays in flight)
            if (wid < 4) { asm volatile("s_waitcnt vmcnt(6)" ::: "memory"); }
            else         { asm volatile("s_waitcnt vmcnt(5)" ::: "memory"); }
        } else {
            asm volatile("s_waitcnt vmcnt(0)" ::: "memory");
        }
        __builtin_amdgcn_s_barrier();                  // buf(c) visible to all waves

        const char* xs = smem + ((c & 1) ? XB1 : XB0);
        const char* bs = smem + ((c & 1) ? BB1 : BB0);
        bf16x8 bfr[6];
#pragma unroll
        for (int n = 0; n < 6; ++n)
            bfr[n] = *reinterpret_cast<const bf16x8*>(bs + lg * 3072 + (wc * 96 + n * 16 + l15) * 16);
        bf16x8 afr[4];
#pragma unroll
        for (int m = 0; m < 4; ++m) {
            int r = wr * 64 + m * 16 + l15;
            int s0 = (2 * lg) ^ (r & 7), s1 = (2 * lg + 1) ^ (r & 7);
            float4 f0 = *reinterpret_cast<const float4*>(xs + r * 128 + s0 * 16);
            float4 f1 = *reinterpret_cast<const float4*>(xs + r * 128 + s1 * 16);
            afr[m][0] = (short)f2bf(f0.x); afr[m][1] = (short)f2bf(f0.y);
            afr[m][2] = (short)f2bf(f0.z); afr[m][3] = (short)f2bf(f0.w);
            afr[m][4] = (short)f2bf(f1.x); afr[m][5] = (short)f2bf(f1.y);
            afr[m][6] = (short)f2bf(f1.z); afr[m][7] = (short)f2bf(f1.w);
        }
#pragma unroll
        for (int m = 0; m < 4; ++m)
#pragma unroll
            for (int n = 0; n < 6; ++n)
                acc[m][n] = __builtin_amdgcn_mfma_f32_16x16x32_bf16(afr[m], bfr[n], acc[m][n], 0, 0, 0);

        __builtin_amdgcn_s_barrier();                  // all waves done with buf(c)
        if (c < 10) issue(c + 2);
    }
    __syncthreads();                                   // x/B bufs dead; safe to overwrite

    // ---------------- stage Q/K/VT to LDS (C/D: col=l15, row=lg*4+j) ----------------
#pragma unroll
    for (int m = 0; m < 4; ++m) {
#pragma unroll
        for (int n = 0; n < 6; ++n) {
            int colb = wc * 96 + n * 16 + l15;
#pragma unroll
            for (int j = 0; j < 4; ++j) {
                int t = wr * 64 + m * 16 + lg * 4 + j;
                unsigned short hv = f2bf(acc[m][n][j]);
                if (colb < 64)
                    *reinterpret_cast<unsigned short*>(smem + QOFF + (t * 72 + colb) * 2) = hv;
                else if (colb < 128)
                    *reinterpret_cast<unsigned short*>(smem + KOFF + (t * 72 + (colb - 64)) * 2) = hv;
                else
                    *reinterpret_cast<unsigned short*>(smem + VTOFF + ((colb - 128) * 264 + t) * 2) = hv;
            }
        }
    }
    __syncthreads();

    // ---------------- phase 2: causal flash attention, 8 waves x 32 rows ------------
    char* Pw = smem + POFF + wid * 4608;               // per-wave P[32][72]
    const int r0 = wid * 32;
    const float scale = 0.05103103630798287f;          // 384^-0.5

    f32x4 o[2][4] = {};
    float M[2][4], L[2][4];
#pragma unroll
    for (int m = 0; m < 2; ++m)
#pragma unroll
        for (int j = 0; j < 4; ++j) { M[m][j] = -1e30f; L[m][j] = 0.f; }

    for (int jt = 0; jt <= (wid >> 1); ++jt) {
        // ---- S = q @ K^T ----
        f32x4 s[2][4] = {};
#pragma unroll
        for (int kk = 0; kk < 2; ++kk) {
            bf16x8 aq[2], bk[4];
#pragma unroll
            for (int m = 0; m < 2; ++m)
                aq[m] = *reinterpret_cast<const bf16x8*>(smem + QOFF + ((r0 + m * 16 + l15) * 72 + kk * 32 + lg * 8) * 2);
#pragma unroll
            for (int n = 0; n < 4; ++n)
                bk[n] = *reinterpret_cast<const bf16x8*>(smem + KOFF + ((jt * 64 + n * 16 + l15) * 72 + kk * 32 + lg * 8) * 2);
#pragma unroll
            for (int m = 0; m < 2; ++m)
#pragma unroll
                for (int n = 0; n < 4; ++n)
                    s[m][n] = __builtin_amdgcn_mfma_f32_16x16x32_bf16(aq[m], bk[n], s[m][n], 0, 0, 0);
        }
        // ---- scale + causal mask + tile row-max ----
        float tm[2][4];
#pragma unroll
        for (int m = 0; m < 2; ++m)
#pragma unroll
            for (int j = 0; j < 4; ++j) tm[m][j] = -1e30f;
#pragma unroll
        for (int m = 0; m < 2; ++m) {
#pragma unroll
            for (int n = 0; n < 4; ++n) {
                int colg = jt * 64 + n * 16 + l15;
#pragma unroll
                for (int j = 0; j < 4; ++j) {
                    int rowg = r0 + m * 16 + lg * 4 + j;
                    float v = s[m][n][j] * scale;
                    if (colg > rowg) v = -1e30f;
                    s[m][n][j] = v;
                    tm[m][j] = fmaxf(tm[m][j], v);
                }
            }
        }
#pragma unroll
        for (int m = 0; m < 2; ++m)
#pragma unroll
            for (int j = 0; j < 4; ++j) {
                float v = tm[m][j];
                v = fmaxf(v, __shfl_xor(v, 1));
                v = fmaxf(v, __shfl_xor(v, 2));
                v = fmaxf(v, __shfl_xor(v, 4));
                v = fmaxf(v, __shfl_xor(v, 8));
                tm[m][j] = v;
            }
        float alpha[2][4];
#pragma unroll
        for (int m = 0; m < 2; ++m)
#pragma unroll
            for (int j = 0; j < 4; ++j) {
                float mn = fmaxf(M[m][j], tm[m][j]);
                alpha[m][j] = __expf(M[m][j] - mn);
                M[m][j] = mn;
            }
        // ---- P = exp(S - M), row-sum ----
        float ts[2][4] = {};
#pragma unroll
        for (int m = 0; m < 2; ++m)
#pragma unroll
            for (int n = 0; n < 4; ++n)
#pragma unroll
                for (int j = 0; j < 4; ++j) {
                    float p = __expf(s[m][n][j] - M[m][j]);
                    s[m][n][j] = p;
                    ts[m][j] += p;
                }
#pragma unroll
        for (int m = 0; m < 2; ++m)
#pragma unroll
            for (int j = 0; j < 4; ++j) {
                float v = ts[m][j];
                v += __shfl_xor(v, 1);
                v += __shfl_xor(v, 2);
                v += __shfl_xor(v, 4);
                v += __shfl_xor(v, 8);
                L[m][j] = L[m][j] * alpha[m][j] + v;
            }
        // ---- rescale O ----
#pragma unroll
        for (int m = 0; m < 2; ++m)
#pragma unroll
            for (int n = 0; n < 4; ++n)
#pragma unroll
                for (int j = 0; j < 4; ++j) o[m][n][j] *= alpha[m][j];
        // ---- P -> per-wave LDS (bf16) ----
#pragma unroll
        for (int m = 0; m < 2; ++m)
#pragma unroll
            for (int n = 0; n < 4; ++n)
#pragma unroll
                for (int j = 0; j < 4; ++j)
                    *reinterpret_cast<unsigned short*>(Pw + ((m * 16 + lg * 4 + j) * 72 + n * 16 + l15) * 2) = f2bf(s[m][n][j]);
        asm volatile("s_waitcnt lgkmcnt(0)" ::: "memory");   // wave-internal LDS RAW fence
        // ---- O += P @ V ----
#pragma unroll
        for (int kk = 0; kk < 2; ++kk) {
            bf16x8 ap[2], bv[4];
#pragma unroll
            for (int m = 0; m < 2; ++m)
                ap[m] = *reinterpret_cast<const bf16x8*>(Pw + ((m * 16 + l15) * 72 + kk * 32 + lg * 8) * 2);
#pragma unroll
            for (int n = 0; n < 4; ++n)
                bv[n] = *reinterpret_cast<const bf16x8*>(smem + VTOFF + ((n * 16 + l15) * 264 + jt * 64 + kk * 32 + lg * 8) * 2);
#pragma unroll
            for (int m = 0; m < 2; ++m)
#pragma unroll
                for (int n = 0; n < 4; ++n)
                    o[m][n] = __builtin_amdgcn_mfma_f32_16x16x32_bf16(ap[m], bv[n], o[m][n], 0, 0, 0);
        }
    }
    // ---- normalize + store fp32 ----
#pragma unroll
    for (int m = 0; m < 2; ++m) {
#pragma unroll
        for (int n = 0; n < 4; ++n) {
            int h = n * 16 + l15;
#pragma unroll
            for (int j = 0; j < 4; ++j) {
                int t = r0 + m * 16 + lg * 4 + j;
                ob[(size_t)t * 64 + h] = o[m][n][j] / L[m][j];
            }
        }
    }
}

extern "C" void kernel_launch(void* const* d_in, const int* in_sizes, int n_in,
                              void* d_out, int out_size, void* d_ws, size_t ws_size,
                              hipStream_t stream) {
    const float* x  = (const float*)d_in[0];
    const float* Wq = (const float*)d_in[1];
    const float* Wk = (const float*)d_in[2];
    const float* Wv = (const float*)d_in[3];
    float* out = (float*)d_out;

    unsigned short* Wt2 = (unsigned short*)d_ws;   // [12][4][192][8] bf16 = 147456 B

    wprep<<<288, 256, 0, stream>>>(Wq, Wk, Wv, Wt2);
    fused<<<256, 512, 0, stream>>>(x, Wt2, out);
}

// Round 8
// 41.088 us; speedup vs baseline: 1.6804x; 1.0988x over previous
//
#include <hip/hip_runtime.h>
#include <hip/hip_bf16.h>

typedef __attribute__((ext_vector_type(8))) short bf16x8;
typedef __attribute__((ext_vector_type(4))) float f32x4;

__device__ __forceinline__ unsigned short f2bf(float f) {
    union { float f; unsigned int u; } v; v.f = f;
    unsigned int u = v.u;
    unsigned int r = u + 0x7FFFu + ((u >> 16) & 1u);   // RNE
    return (unsigned short)(r >> 16);
}

__device__ __forceinline__ unsigned int cvtpk(float lo, float hi) {
    unsigned int r;
    asm("v_cvt_pk_bf16_f32 %0, %1, %2" : "=v"(r) : "v"(lo), "v"(hi));
    return r;
}

#define GLDS16(gsrc, ldst)                                                          \
    __builtin_amdgcn_global_load_lds(                                               \
        (const __attribute__((address_space(1))) unsigned int*)(gsrc),              \
        (__attribute__((address_space(3))) unsigned int*)(ldst), 16, 0, 0)

// ---------------- kernel 0: W -> Wt2 [c=12][kc2=4][col=192][8] bf16 ----------------
__global__ __launch_bounds__(256) void wprep(const float* __restrict__ Wq,
                                             const float* __restrict__ Wk,
                                             const float* __restrict__ Wv,
                                             unsigned short* __restrict__ Wt2) {
    int idx = blockIdx.x * 256 + threadIdx.x;          // 3*64*384 = 73728
    if (idx >= 73728) return;
    int w   = idx / 24576;
    int rem = idx % 24576;
    int n = rem / 384, k = rem % 384;
    const float* W = (w == 0) ? Wq : ((w == 1) ? Wk : Wv);
    int col = w * 64 + n;
    Wt2[(size_t)(k >> 5) * 6144 + ((k >> 3) & 3) * 1536 + col * 8 + (k & 7)] = f2bf(W[k * 64 + n]);
}

// ---------------- fused kernel: one block per batch, 512 threads / 8 waves ----------
// Phase 1 (barrier-free K-loop): B fully LDS-resident (147456B, staged once);
//   wave w computes rows w*32..w*32+32 x all 192 cols (acc[2][12]); x loads are
//   per-wave register loads used directly as A-fragments, 3-deep named rotation
//   with counted vmcnt — waves drift freely, loads stay in flight continuously.
// Phase 2: write Q/K/VT to LDS (overwrites B), causal flash attention (R7 code).
#define QOFF  0
#define KOFF  36864
#define VTOFF 73728
#define POFF  107520

__global__ __launch_bounds__(512, 2) void fused(const float* __restrict__ x,
                                                const unsigned short* __restrict__ Wt2,
                                                float* __restrict__ out) {
    __shared__ __align__(16) char smem[147456];

    const int b = blockIdx.x;
    const int tid = threadIdx.x, lane = tid & 63, wid = tid >> 6;
    const int l15 = lane & 15, lg = lane >> 4;
    const float* xb = x + (size_t)b * 98304;
    float* ob = out + (size_t)b * 16384;

    // ---- stage ALL of B once: 18 glds/wave, linear ----
#pragma unroll
    for (int i = 0; i < 18; ++i) {
        int n = wid * 18 + i;
        GLDS16(Wt2 + (size_t)n * 512 + lane * 8, smem + n * 1024);
    }

    // ---- x pointers: wave w rows w*32 + {0,16} + l15, k-offset lg*8 ----
    const float* xw = xb + (size_t)(wid * 32 + l15) * 384 + lg * 8;

    float4 p0[4], p1[4], p2[4];
#define XLOAD(P, C)                                                                 \
    P[0] = *reinterpret_cast<const float4*>(xw + (C) * 32);                         \
    P[1] = *reinterpret_cast<const float4*>(xw + (C) * 32 + 4);                     \
    P[2] = *reinterpret_cast<const float4*>(xw + 6144 + (C) * 32);                  \
    P[3] = *reinterpret_cast<const float4*>(xw + 6144 + (C) * 32 + 4);
    XLOAD(p0, 0)
    XLOAD(p1, 1)
    XLOAD(p2, 2)
    __builtin_amdgcn_sched_barrier(0);
    asm volatile("s_waitcnt vmcnt(12)" ::: "memory");   // all B glds landed; x 0..2 in flight
    __builtin_amdgcn_s_barrier();                       // B visible to all waves

    f32x4 acc[2][12] = {};

#define CHUNK(C, P, WAITN)                                                          \
    asm volatile("s_waitcnt vmcnt(" #WAITN ")" ::: "memory");                       \
    __builtin_amdgcn_sched_barrier(0);                                              \
    {                                                                               \
        union { unsigned int u[4]; bf16x8 v; } cv0, cv1;                            \
        cv0.u[0] = cvtpk(P[0].x, P[0].y); cv0.u[1] = cvtpk(P[0].z, P[0].w);         \
        cv0.u[2] = cvtpk(P[1].x, P[1].y); cv0.u[3] = cvtpk(P[1].z, P[1].w);         \
        cv1.u[0] = cvtpk(P[2].x, P[2].y); cv1.u[1] = cvtpk(P[2].z, P[2].w);         \
        cv1.u[2] = cvtpk(P[3].x, P[3].y); cv1.u[3] = cvtpk(P[3].z, P[3].w);         \
        bf16x8 a0 = cv0.v, a1 = cv1.v;                                              \
        if ((C) + 3 < 12) { XLOAD(P, (C) + 3) }                                     \
        __builtin_amdgcn_sched_barrier(0);                                          \
        const char* bs = smem + (C) * 12288 + lg * 3072 + l15 * 16;                 \
        _Pragma("unroll")                                                           \
        for (int n = 0; n < 12; ++n) {                                              \
            bf16x8 bf = *reinterpret_cast<const bf16x8*>(bs + n * 256);             \
            acc[0][n] = __builtin_amdgcn_mfma_f32_16x16x32_bf16(a0, bf, acc[0][n], 0, 0, 0); \
            acc[1][n] = __builtin_amdgcn_mfma_f32_16x16x32_bf16(a1, bf, acc[1][n], 0, 0, 0); \
        }                                                                           \
    }

    CHUNK(0,  p0, 8)
    CHUNK(1,  p1, 8)
    CHUNK(2,  p2, 8)
    CHUNK(3,  p0, 8)
    CHUNK(4,  p1, 8)
    CHUNK(5,  p2, 8)
    CHUNK(6,  p0, 8)
    CHUNK(7,  p1, 8)
    CHUNK(8,  p2, 8)
    CHUNK(9,  p0, 8)
    CHUNK(10, p1, 4)
    CHUNK(11, p2, 0)

    __syncthreads();                                    // all waves done reading B

    // ---- stage Q/K/VT to LDS (C/D layout: col=l15, row=lg*4+j) ----
#pragma unroll
    for (int m = 0; m < 2; ++m) {
#pragma unroll
        for (int n = 0; n < 12; ++n) {
            int col = n * 16 + l15;
#pragma unroll
            for (int j = 0; j < 4; ++j) {
                int t = wid * 32 + m * 16 + lg * 4 + j;
                unsigned short hv = f2bf(acc[m][n][j]);
                if (col < 64)
                    *reinterpret_cast<unsigned short*>(smem + QOFF + (t * 72 + col) * 2) = hv;
                else if (col < 128)
                    *reinterpret_cast<unsigned short*>(smem + KOFF + (t * 72 + (col - 64)) * 2) = hv;
                else
                    *reinterpret_cast<unsigned short*>(smem + VTOFF + ((col - 128) * 264 + t) * 2) = hv;
            }
        }
    }
    __syncthreads();

    // ---------------- phase 2: causal flash attention, 8 waves x 32 rows ------------
    char* Pw = smem + POFF + wid * 4608;               // per-wave P[32][72]
    const int r0 = wid * 32;
    const float scale = 0.05103103630798287f;          // 384^-0.5

    f32x4 o[2][4] = {};
    float M[2][4], L[2][4];
#pragma unroll
    for (int m = 0; m < 2; ++m)
#pragma unroll
        for (int j = 0; j < 4; ++j) { M[m][j] = -1e30f; L[m][j] = 0.f; }

    for (int jt = 0; jt <= (wid >> 1); ++jt) {
        // ---- S = q @ K^T ----
        f32x4 s[2][4] = {};
#pragma unroll
        for (int kk = 0; kk < 2; ++kk) {
            bf16x8 aq[2], bk[4];
#pragma unroll
            for (int m = 0; m < 2; ++m)
                aq[m] = *reinterpret_cast<const bf16x8*>(smem + QOFF + ((r0 + m * 16 + l15) * 72 + kk * 32 + lg * 8) * 2);
#pragma unroll
            for (int n = 0; n < 4; ++n)
                bk[n] = *reinterpret_cast<const bf16x8*>(smem + KOFF + ((jt * 64 + n * 16 + l15) * 72 + kk * 32 + lg * 8) * 2);
#pragma unroll
            for (int m = 0; m < 2; ++m)
#pragma unroll
                for (int n = 0; n < 4; ++n)
                    s[m][n] = __builtin_amdgcn_mfma_f32_16x16x32_bf16(aq[m], bk[n], s[m][n], 0, 0, 0);
        }
        // ---- scale + causal mask + tile row-max ----
        float tm[2][4];
#pragma unroll
        for (int m = 0; m < 2; ++m)
#pragma unroll
            for (int j = 0; j < 4; ++j) tm[m][j] = -1e30f;
#pragma unroll
        for (int m = 0; m < 2; ++m) {
#pragma unroll
            for (int n = 0; n < 4; ++n) {
                int colg = jt * 64 + n * 16 + l15;
#pragma unroll
                for (int j = 0; j < 4; ++j) {
                    int rowg = r0 + m * 16 + lg * 4 + j;
                    float v = s[m][n][j] * scale;
                    if (colg > rowg) v = -1e30f;
                    s[m][n][j] = v;
                    tm[m][j] = fmaxf(tm[m][j], v);
                }
            }
        }
#pragma unroll
        for (int m = 0; m < 2; ++m)
#pragma unroll
            for (int j = 0; j < 4; ++j) {
                float v = tm[m][j];
                v = fmaxf(v, __shfl_xor(v, 1));
                v = fmaxf(v, __shfl_xor(v, 2));
                v = fmaxf(v, __shfl_xor(v, 4));
                v = fmaxf(v, __shfl_xor(v, 8));
                tm[m][j] = v;
            }
        float alpha[2][4];
#pragma unroll
        for (int m = 0; m < 2; ++m)
#pragma unroll
            for (int j = 0; j < 4; ++j) {
                float mn = fmaxf(M[m][j], tm[m][j]);
                alpha[m][j] = __expf(M[m][j] - mn);
                M[m][j] = mn;
            }
        // ---- P = exp(S - M), row-sum ----
        float ts[2][4] = {};
#pragma unroll
        for (int m = 0; m < 2; ++m)
#pragma unroll
            for (int n = 0; n < 4; ++n)
#pragma unroll
                for (int j = 0; j < 4; ++j) {
                    float p = __expf(s[m][n][j] - M[m][j]);
                    s[m][n][j] = p;
                    ts[m][j] += p;
                }
#pragma unroll
        for (int m = 0; m < 2; ++m)
#pragma unroll
            for (int j = 0; j < 4; ++j) {
                float v = ts[m][j];
                v += __shfl_xor(v, 1);
                v += __shfl_xor(v, 2);
                v += __shfl_xor(v, 4);
                v += __shfl_xor(v, 8);
                L[m][j] = L[m][j] * alpha[m][j] + v;
            }
        // ---- rescale O ----
#pragma unroll
        for (int m = 0; m < 2; ++m)
#pragma unroll
            for (int n = 0; n < 4; ++n)
#pragma unroll
                for (int j = 0; j < 4; ++j) o[m][n][j] *= alpha[m][j];
        // ---- P -> per-wave LDS (bf16) ----
#pragma unroll
        for (int m = 0; m < 2; ++m)
#pragma unroll
            for (int n = 0; n < 4; ++n)
#pragma unroll
                for (int j = 0; j < 4; ++j)
                    *reinterpret_cast<unsigned short*>(Pw + ((m * 16 + lg * 4 + j) * 72 + n * 16 + l15) * 2) = f2bf(s[m][n][j]);
        asm volatile("s_waitcnt lgkmcnt(0)" ::: "memory");   // wave-internal LDS RAW fence
        // ---- O += P @ V ----
#pragma unroll
        for (int kk = 0; kk < 2; ++kk) {
            bf16x8 ap[2], bv[4];
#pragma unroll
            for (int m = 0; m < 2; ++m)
                ap[m] = *reinterpret_cast<const bf16x8*>(Pw + ((m * 16 + l15) * 72 + kk * 32 + lg * 8) * 2);
#pragma unroll
            for (int n = 0; n < 4; ++n)
                bv[n] = *reinterpret_cast<const bf16x8*>(smem + VTOFF + ((n * 16 + l15) * 264 + jt * 64 + kk * 32 + lg * 8) * 2);
#pragma unroll
            for (int m = 0; m < 2; ++m)
#pragma unroll
                for (int n = 0; n < 4; ++n)
                    o[m][n] = __builtin_amdgcn_mfma_f32_16x16x32_bf16(ap[m], bv[n], o[m][n], 0, 0, 0);
        }
    }
    // ---- normalize + store fp32 ----
#pragma unroll
    for (int m = 0; m < 2; ++m) {
#pragma unroll
        for (int n = 0; n < 4; ++n) {
            int h = n * 16 + l15;
#pragma unroll
            for (int j = 0; j < 4; ++j) {
                int t = r0 + m * 16 + lg * 4 + j;
                ob[(size_t)t * 64 + h] = o[m][n][j] / L[m][j];
            }
        }
    }
}

extern "C" void kernel_launch(void* const* d_in, const int* in_sizes, int n_in,
                              void* d_out, int out_size, void* d_ws, size_t ws_size,
                              hipStream_t stream) {
    const float* x  = (const float*)d_in[0];
    const float* Wq = (const float*)d_in[1];
    const float* Wk = (const float*)d_in[2];
    const float* Wv = (const float*)d_in[3];
    float* out = (float*)d_out;

    unsigned short* Wt2 = (unsigned short*)d_ws;   // [12][4][192][8] bf16 = 147456 B

    wprep<<<288, 256, 0, stream>>>(Wq, Wk, Wv, Wt2);
    fused<<<256, 512, 0, stream>>>(x, Wt2, out);
}

// Round 9
// 39.888 us; speedup vs baseline: 1.7309x; 1.0301x over previous
//
#include <hip/hip_runtime.h>
#include <hip/hip_bf16.h>

typedef __attribute__((ext_vector_type(8))) short bf16x8;
typedef __attribute__((ext_vector_type(4))) float f32x4;

__device__ __forceinline__ unsigned short f2bf(float f) {
    union { float f; unsigned int u; } v; v.f = f;
    unsigned int u = v.u;
    unsigned int r = u + 0x7FFFu + ((u >> 16) & 1u);   // RNE
    return (unsigned short)(r >> 16);
}

__device__ __forceinline__ unsigned int cvtpk(float lo, float hi) {
    unsigned int r;
    asm("v_cvt_pk_bf16_f32 %0, %1, %2" : "=v"(r) : "v"(lo), "v"(hi));
    return r;
}

#define GLDS16(gsrc, ldst)                                                          \
    __builtin_amdgcn_global_load_lds(                                               \
        (const __attribute__((address_space(1))) unsigned int*)(gsrc),              \
        (__attribute__((address_space(3))) unsigned int*)(ldst), 16, 0, 0)

// ---------------- kernel 0: W -> Wt2 [c=12][kc2=4][col=192][8] bf16 ----------------
__global__ __launch_bounds__(256) void wprep(const float* __restrict__ Wq,
                                             const float* __restrict__ Wk,
                                             const float* __restrict__ Wv,
                                             unsigned short* __restrict__ Wt2) {
    int idx = blockIdx.x * 256 + threadIdx.x;          // 3*64*384 = 73728
    if (idx >= 73728) return;
    int w   = idx / 24576;
    int rem = idx % 24576;
    int n = rem / 384, k = rem % 384;
    const float* W = (w == 0) ? Wq : ((w == 1) ? Wk : Wv);
    int col = w * 64 + n;
    Wt2[(size_t)(k >> 5) * 6144 + ((k >> 3) & 3) * 1536 + col * 8 + (k & 7)] = f2bf(W[k * 64 + n]);
}

// ---------------- fused kernel: one block per batch, 1024 threads / 16 waves --------
// Phase 1 (barrier-free K-loop): B fully LDS-resident (147456B, staged once);
//   wave w computes rows w*16..w*16+16 x all 192 cols (acc[1][12]); x loads are
//   per-wave register loads used directly as A-fragments, 3-deep named rotation
//   with counted vmcnt — waves drift freely, 4 waves/SIMD cover the stalls.
// Phase 2: write Q/K/VT to LDS (overwrites B), causal flash attention, 16 waves.
#define QOFF  0
#define KOFF  36864
#define VTOFF 73728
#define POFF  107520

__global__ __launch_bounds__(1024) void fused(const float* __restrict__ x,
                                              const unsigned short* __restrict__ Wt2,
                                              float* __restrict__ out) {
    __shared__ __align__(16) char smem[147456];

    const int b = blockIdx.x;
    const int tid = threadIdx.x, lane = tid & 63, wid = tid >> 6;   // wid 0..15
    const int l15 = lane & 15, lg = lane >> 4;
    const float* xb = x + (size_t)b * 98304;
    float* ob = out + (size_t)b * 16384;

    // ---- stage ALL of B once: 9 glds/wave, linear ----
#pragma unroll
    for (int i = 0; i < 9; ++i) {
        int n = wid * 9 + i;
        GLDS16(Wt2 + (size_t)n * 512 + lane * 8, smem + n * 1024);
    }

    // ---- x pointer: wave w row w*16 + l15, k-offset lg*8 ----
    const float* xw = xb + (size_t)(wid * 16 + l15) * 384 + lg * 8;

    float4 p0[2], p1[2], p2[2];
#define XLOAD(P, C)                                                                 \
    P[0] = *reinterpret_cast<const float4*>(xw + (C) * 32);                         \
    P[1] = *reinterpret_cast<const float4*>(xw + (C) * 32 + 4);
    XLOAD(p0, 0)
    XLOAD(p1, 1)
    XLOAD(p2, 2)
    __builtin_amdgcn_sched_barrier(0);
    asm volatile("s_waitcnt vmcnt(6)" ::: "memory");    // all 9 B glds landed; x 0..2 in flight
    __builtin_amdgcn_s_barrier();                       // B visible to all waves

    f32x4 acc[12] = {};

#define CHUNK(C, P, WAITN)                                                          \
    asm volatile("s_waitcnt vmcnt(" #WAITN ")" ::: "memory");                       \
    __builtin_amdgcn_sched_barrier(0);                                              \
    {                                                                               \
        union { unsigned int u[4]; bf16x8 v; } cv0;                                 \
        cv0.u[0] = cvtpk(P[0].x, P[0].y); cv0.u[1] = cvtpk(P[0].z, P[0].w);         \
        cv0.u[2] = cvtpk(P[1].x, P[1].y); cv0.u[3] = cvtpk(P[1].z, P[1].w);         \
        bf16x8 a0 = cv0.v;                                                          \
        if ((C) + 3 < 12) { XLOAD(P, (C) + 3) }                                     \
        __builtin_amdgcn_sched_barrier(0);                                          \
        const char* bs = smem + (C) * 12288 + lg * 3072 + l15 * 16;                 \
        _Pragma("unroll")                                                           \
        for (int n = 0; n < 12; ++n) {                                              \
            bf16x8 bf = *reinterpret_cast<const bf16x8*>(bs + n * 256);             \
            acc[n] = __builtin_amdgcn_mfma_f32_16x16x32_bf16(a0, bf, acc[n], 0, 0, 0); \
        }                                                                           \
    }

    CHUNK(0,  p0, 4)
    CHUNK(1,  p1, 4)
    CHUNK(2,  p2, 4)
    CHUNK(3,  p0, 4)
    CHUNK(4,  p1, 4)
    CHUNK(5,  p2, 4)
    CHUNK(6,  p0, 4)
    CHUNK(7,  p1, 4)
    CHUNK(8,  p2, 4)
    CHUNK(9,  p0, 4)
    CHUNK(10, p1, 2)
    CHUNK(11, p2, 0)

    __syncthreads();                                    // all waves done reading B

    // ---- stage Q/K/VT to LDS (C/D layout: col=l15, row=lg*4+j) ----
#pragma unroll
    for (int n = 0; n < 12; ++n) {
        int col = n * 16 + l15;
#pragma unroll
        for (int j = 0; j < 4; ++j) {
            int t = wid * 16 + lg * 4 + j;
            unsigned short hv = f2bf(acc[n][j]);
            if (col < 64)
                *reinterpret_cast<unsigned short*>(smem + QOFF + (t * 72 + col) * 2) = hv;
            else if (col < 128)
                *reinterpret_cast<unsigned short*>(smem + KOFF + (t * 72 + (col - 64)) * 2) = hv;
            else
                *reinterpret_cast<unsigned short*>(smem + VTOFF + ((col - 128) * 264 + t) * 2) = hv;
        }
    }
    __syncthreads();

    // ---------------- phase 2: causal flash attention, 16 waves x 16 rows -----------
    char* Pw = smem + POFF + wid * 2304;               // per-wave P[16][72]
    const int r0 = wid * 16;
    const float scale = 0.05103103630798287f;          // 384^-0.5

    f32x4 o[4] = {};
    float M[4], L[4];
#pragma unroll
    for (int j = 0; j < 4; ++j) { M[j] = -1e30f; L[j] = 0.f; }

    for (int jt = 0; jt <= (wid >> 2); ++jt) {
        // ---- S = q @ K^T ----
        f32x4 s[4] = {};
#pragma unroll
        for (int kk = 0; kk < 2; ++kk) {
            bf16x8 aq, bk[4];
            aq = *reinterpret_cast<const bf16x8*>(smem + QOFF + ((r0 + l15) * 72 + kk * 32 + lg * 8) * 2);
#pragma unroll
            for (int n = 0; n < 4; ++n)
                bk[n] = *reinterpret_cast<const bf16x8*>(smem + KOFF + ((jt * 64 + n * 16 + l15) * 72 + kk * 32 + lg * 8) * 2);
#pragma unroll
            for (int n = 0; n < 4; ++n)
                s[n] = __builtin_amdgcn_mfma_f32_16x16x32_bf16(aq, bk[n], s[n], 0, 0, 0);
        }
        // ---- scale + causal mask + tile row-max ----
        float tm[4];
#pragma unroll
        for (int j = 0; j < 4; ++j) tm[j] = -1e30f;
#pragma unroll
        for (int n = 0; n < 4; ++n) {
            int colg = jt * 64 + n * 16 + l15;
#pragma unroll
            for (int j = 0; j < 4; ++j) {
                int rowg = r0 + lg * 4 + j;
                float v = s[n][j] * scale;
                if (colg > rowg) v = -1e30f;
                s[n][j] = v;
                tm[j] = fmaxf(tm[j], v);
            }
        }
#pragma unroll
        for (int j = 0; j < 4; ++j) {
            float v = tm[j];
            v = fmaxf(v, __shfl_xor(v, 1));
            v = fmaxf(v, __shfl_xor(v, 2));
            v = fmaxf(v, __shfl_xor(v, 4));
            v = fmaxf(v, __shfl_xor(v, 8));
            tm[j] = v;
        }
        float alpha[4];
#pragma unroll
        for (int j = 0; j < 4; ++j) {
            float mn = fmaxf(M[j], tm[j]);
            alpha[j] = __expf(M[j] - mn);
            M[j] = mn;
        }
        // ---- P = exp(S - M), row-sum ----
        float ts[4] = {};
#pragma unroll
        for (int n = 0; n < 4; ++n)
#pragma unroll
            for (int j = 0; j < 4; ++j) {
                float p = __expf(s[n][j] - M[j]);
                s[n][j] = p;
                ts[j] += p;
            }
#pragma unroll
        for (int j = 0; j < 4; ++j) {
            float v = ts[j];
            v += __shfl_xor(v, 1);
            v += __shfl_xor(v, 2);
            v += __shfl_xor(v, 4);
            v += __shfl_xor(v, 8);
            L[j] = L[j] * alpha[j] + v;
        }
        // ---- rescale O ----
#pragma unroll
        for (int n = 0; n < 4; ++n)
#pragma unroll
            for (int j = 0; j < 4; ++j) o[n][j] *= alpha[j];
        // ---- P -> per-wave LDS (bf16) ----
#pragma unroll
        for (int n = 0; n < 4; ++n)
#pragma unroll
            for (int j = 0; j < 4; ++j)
                *reinterpret_cast<unsigned short*>(Pw + ((lg * 4 + j) * 72 + n * 16 + l15) * 2) = f2bf(s[n][j]);
        asm volatile("s_waitcnt lgkmcnt(0)" ::: "memory");   // wave-internal LDS RAW fence
        // ---- O += P @ V ----
#pragma unroll
        for (int kk = 0; kk < 2; ++kk) {
            bf16x8 ap, bv[4];
            ap = *reinterpret_cast<const bf16x8*>(Pw + (l15 * 72 + kk * 32 + lg * 8) * 2);
#pragma unroll
            for (int n = 0; n < 4; ++n)
                bv[n] = *reinterpret_cast<const bf16x8*>(smem + VTOFF + ((n * 16 + l15) * 264 + jt * 64 + kk * 32 + lg * 8) * 2);
#pragma unroll
            for (int n = 0; n < 4; ++n)
                o[n] = __builtin_amdgcn_mfma_f32_16x16x32_bf16(ap, bv[n], o[n], 0, 0, 0);
        }
    }
    // ---- normalize + store fp32 ----
#pragma unroll
    for (int n = 0; n < 4; ++n) {
        int h = n * 16 + l15;
#pragma unroll
        for (int j = 0; j < 4; ++j) {
            int t = r0 + lg * 4 + j;
            ob[(size_t)t * 64 + h] = o[n][j] / L[j];
        }
    }
}

extern "C" void kernel_launch(void* const* d_in, const int* in_sizes, int n_in,
                              void* d_out, int out_size, void* d_ws, size_t ws_size,
                              hipStream_t stream) {
    const float* x  = (const float*)d_in[0];
    const float* Wq = (const float*)d_in[1];
    const float* Wk = (const float*)d_in[2];
    const float* Wv = (const float*)d_in[3];
    float* out = (float*)d_out;

    unsigned short* Wt2 = (unsigned short*)d_ws;   // [12][4][192][8] bf16 = 147456 B

    wprep<<<288, 256, 0, stream>>>(Wq, Wk, Wv, Wt2);
    fused<<<256, 1024, 0, stream>>>(x, Wt2, out);
}

// Round 10
// 39.487 us; speedup vs baseline: 1.7485x; 1.0102x over previous
//
#include <hip/hip_runtime.h>
#include <hip/hip_bf16.h>

typedef __attribute__((ext_vector_type(8))) short bf16x8;
typedef __attribute__((ext_vector_type(4))) float f32x4;

__device__ __forceinline__ unsigned short f2bf(float f) {
    union { float f; unsigned int u; } v; v.f = f;
    unsigned int u = v.u;
    unsigned int r = u + 0x7FFFu + ((u >> 16) & 1u);   // RNE
    return (unsigned short)(r >> 16);
}

__device__ __forceinline__ unsigned int cvtpk(float lo, float hi) {
    unsigned int r;
    asm("v_cvt_pk_bf16_f32 %0, %1, %2" : "=v"(r) : "v"(lo), "v"(hi));
    return r;
}

#define GLDS16(gsrc, ldst)                                                          \
    __builtin_amdgcn_global_load_lds(                                               \
        (const __attribute__((address_space(1))) unsigned int*)(gsrc),              \
        (__attribute__((address_space(3))) unsigned int*)(ldst), 16, 0, 0)

// ---------------- kernel 0: W -> Wt2 [c=12][kc2=4][col=192][8] bf16 ----------------
__global__ __launch_bounds__(256) void wprep(const float* __restrict__ Wq,
                                             const float* __restrict__ Wk,
                                             const float* __restrict__ Wv,
                                             unsigned short* __restrict__ Wt2) {
    int idx = blockIdx.x * 256 + threadIdx.x;          // 3*64*384 = 73728
    if (idx >= 73728) return;
    int w   = idx / 24576;
    int rem = idx % 24576;
    int n = rem / 384, k = rem % 384;
    const float* W = (w == 0) ? Wq : ((w == 1) ? Wk : Wv);
    int col = w * 64 + n;
    Wt2[(size_t)(k >> 5) * 6144 + ((k >> 3) & 3) * 1536 + col * 8 + (k & 7)] = f2bf(W[k * 64 + n]);
}

#define QOFF  0
#define KOFF  36864
#define VTOFF 73728
#define POFF  107520

// ---------------- phase 2 helper: single-pass softmax attention strip ---------------
// Wave owns 32 Q-rows at r0; NT causal 64-col tiles. All S tiles in registers,
// one max/sum reduce per wave, then per-tile P-write + PV.
template<int NT>
__device__ __forceinline__ void attn_strip(char* smem, char* Pw, float* ob,
                                           int r0, int l15, int lg) {
    const float scale = 0.05103103630798287f;          // 384^-0.5

    bf16x8 aq[2][2];
#pragma unroll
    for (int m = 0; m < 2; ++m)
#pragma unroll
        for (int kk = 0; kk < 2; ++kk)
            aq[m][kk] = *reinterpret_cast<const bf16x8*>(smem + QOFF + ((r0 + m * 16 + l15) * 72 + kk * 32 + lg * 8) * 2);

    f32x4 s[NT][2][4] = {};
#pragma unroll
    for (int jt = 0; jt < NT; ++jt) {
#pragma unroll
        for (int kk = 0; kk < 2; ++kk) {
            bf16x8 bk[4];
#pragma unroll
            for (int n = 0; n < 4; ++n)
                bk[n] = *reinterpret_cast<const bf16x8*>(smem + KOFF + ((jt * 64 + n * 16 + l15) * 72 + kk * 32 + lg * 8) * 2);
#pragma unroll
            for (int m = 0; m < 2; ++m)
#pragma unroll
                for (int n = 0; n < 4; ++n)
                    s[jt][m][n] = __builtin_amdgcn_mfma_f32_16x16x32_bf16(aq[m][kk], bk[n], s[jt][m][n], 0, 0, 0);
        }
    }
    // scale + causal mask + global row-max
    float M[2][4];
#pragma unroll
    for (int m = 0; m < 2; ++m)
#pragma unroll
        for (int j = 0; j < 4; ++j) M[m][j] = -1e30f;
#pragma unroll
    for (int jt = 0; jt < NT; ++jt)
#pragma unroll
        for (int m = 0; m < 2; ++m)
#pragma unroll
            for (int n = 0; n < 4; ++n) {
                int colg = jt * 64 + n * 16 + l15;
#pragma unroll
                for (int j = 0; j < 4; ++j) {
                    int rowg = r0 + m * 16 + lg * 4 + j;
                    float v = s[jt][m][n][j] * scale;
                    if (colg > rowg) v = -1e30f;
                    s[jt][m][n][j] = v;
                    M[m][j] = fmaxf(M[m][j], v);
                }
            }
#pragma unroll
    for (int m = 0; m < 2; ++m)
#pragma unroll
        for (int j = 0; j < 4; ++j) {
            float v = M[m][j];
            v = fmaxf(v, __shfl_xor(v, 1));
            v = fmaxf(v, __shfl_xor(v, 2));
            v = fmaxf(v, __shfl_xor(v, 4));
            v = fmaxf(v, __shfl_xor(v, 8));
            M[m][j] = v;
        }
    // exp + global row-sum
    float L[2][4] = {};
#pragma unroll
    for (int jt = 0; jt < NT; ++jt)
#pragma unroll
        for (int m = 0; m < 2; ++m)
#pragma unroll
            for (int n = 0; n < 4; ++n)
#pragma unroll
                for (int j = 0; j < 4; ++j) {
                    float p = __expf(s[jt][m][n][j] - M[m][j]);
                    s[jt][m][n][j] = p;
                    L[m][j] += p;
                }
#pragma unroll
    for (int m = 0; m < 2; ++m)
#pragma unroll
        for (int j = 0; j < 4; ++j) {
            float v = L[m][j];
            v += __shfl_xor(v, 1);
            v += __shfl_xor(v, 2);
            v += __shfl_xor(v, 4);
            v += __shfl_xor(v, 8);
            L[m][j] = v;
        }
    // per-tile: P -> LDS, PV accumulate
    f32x4 o[2][4] = {};
#pragma unroll
    for (int jt = 0; jt < NT; ++jt) {
#pragma unroll
        for (int m = 0; m < 2; ++m)
#pragma unroll
            for (int n = 0; n < 4; ++n)
#pragma unroll
                for (int j = 0; j < 4; ++j)
                    *reinterpret_cast<unsigned short*>(Pw + ((m * 16 + lg * 4 + j) * 72 + n * 16 + l15) * 2) = f2bf(s[jt][m][n][j]);
        asm volatile("s_waitcnt lgkmcnt(0)" ::: "memory");   // wave-internal LDS RAW fence
#pragma unroll
        for (int kk = 0; kk < 2; ++kk) {
            bf16x8 ap[2], bv[4];
#pragma unroll
            for (int m = 0; m < 2; ++m)
                ap[m] = *reinterpret_cast<const bf16x8*>(Pw + ((m * 16 + l15) * 72 + kk * 32 + lg * 8) * 2);
#pragma unroll
            for (int n = 0; n < 4; ++n)
                bv[n] = *reinterpret_cast<const bf16x8*>(smem + VTOFF + ((n * 16 + l15) * 264 + jt * 64 + kk * 32 + lg * 8) * 2);
#pragma unroll
            for (int m = 0; m < 2; ++m)
#pragma unroll
                for (int n = 0; n < 4; ++n)
                    o[m][n] = __builtin_amdgcn_mfma_f32_16x16x32_bf16(ap[m], bv[n], o[m][n], 0, 0, 0);
        }
    }
    // normalize + store
#pragma unroll
    for (int m = 0; m < 2; ++m)
#pragma unroll
        for (int n = 0; n < 4; ++n) {
            int h = n * 16 + l15;
#pragma unroll
            for (int j = 0; j < 4; ++j) {
                int t = r0 + m * 16 + lg * 4 + j;
                ob[(size_t)t * 64 + h] = o[m][n][j] / L[m][j];
            }
        }
}

// ---------------- fused kernel: one block per batch, 512 threads / 8 waves ----------
__global__ __launch_bounds__(512, 1) void fused(const float* __restrict__ x,
                                                const unsigned short* __restrict__ Wt2,
                                                float* __restrict__ out) {
    __shared__ __align__(16) char smem[147456];

    const int b = blockIdx.x;
    const int tid = threadIdx.x, lane = tid & 63, wid = tid >> 6;   // wid 0..7
    const int l15 = lane & 15, lg = lane >> 4;
    const float* xb = x + (size_t)b * 98304;
    float* ob = out + (size_t)b * 16384;

    // ---- stage ALL of B once: 18 glds/wave, linear ----
#pragma unroll
    for (int i = 0; i < 18; ++i) {
        int n = wid * 18 + i;
        GLDS16(Wt2 + (size_t)n * 512 + lane * 8, smem + n * 1024);
    }

    // ---- x pointer: wave w rows w*32 + {0,16} + l15, k-offset lg*8 ----
    const float* xw = xb + (size_t)(wid * 32 + l15) * 384 + lg * 8;

    float4 p0[4], p1[4], p2[4], p3[4], p4[4];
#define XLOAD(P, C)                                                                 \
    P[0] = *reinterpret_cast<const float4*>(xw + (C) * 32);                         \
    P[1] = *reinterpret_cast<const float4*>(xw + (C) * 32 + 4);                     \
    P[2] = *reinterpret_cast<const float4*>(xw + 6144 + (C) * 32);                  \
    P[3] = *reinterpret_cast<const float4*>(xw + 6144 + (C) * 32 + 4);
    XLOAD(p0, 0)
    XLOAD(p1, 1)
    XLOAD(p2, 2)
    XLOAD(p3, 3)
    XLOAD(p4, 4)
    __builtin_amdgcn_sched_barrier(0);
    asm volatile("s_waitcnt vmcnt(20)" ::: "memory");   // 18 B glds landed; x 0..4 in flight
    __builtin_amdgcn_s_barrier();                       // B visible to all waves

    f32x4 acc[2][12] = {};

#define CHUNK(C, P, WAITN)                                                          \
    asm volatile("s_waitcnt vmcnt(" #WAITN ")" ::: "memory");                       \
    __builtin_amdgcn_sched_barrier(0);                                              \
    {                                                                               \
        union { unsigned int u[4]; bf16x8 v; } cv0, cv1;                            \
        cv0.u[0] = cvtpk(P[0].x, P[0].y); cv0.u[1] = cvtpk(P[0].z, P[0].w);         \
        cv0.u[2] = cvtpk(P[1].x, P[1].y); cv0.u[3] = cvtpk(P[1].z, P[1].w);         \
        cv1.u[0] = cvtpk(P[2].x, P[2].y); cv1.u[1] = cvtpk(P[2].z, P[2].w);         \
        cv1.u[2] = cvtpk(P[3].x, P[3].y); cv1.u[3] = cvtpk(P[3].z, P[3].w);         \
        bf16x8 a0 = cv0.v, a1 = cv1.v;                                              \
        if ((C) + 5 < 12) { XLOAD(P, (C) + 5) }                                     \
        __builtin_amdgcn_sched_barrier(0);                                          \
        const char* bs = smem + (C) * 12288 + lg * 3072 + l15 * 16;                 \
        _Pragma("unroll")                                                           \
        for (int n = 0; n < 12; ++n) {                                              \
            bf16x8 bf = *reinterpret_cast<const bf16x8*>(bs + n * 256);             \
            acc[0][n] = __builtin_amdgcn_mfma_f32_16x16x32_bf16(a0, bf, acc[0][n], 0, 0, 0); \
            acc[1][n] = __builtin_amdgcn_mfma_f32_16x16x32_bf16(a1, bf, acc[1][n], 0, 0, 0); \
        }                                                                           \
    }

    CHUNK(0,  p0, 16)
    CHUNK(1,  p1, 16)
    CHUNK(2,  p2, 16)
    CHUNK(3,  p3, 16)
    CHUNK(4,  p4, 16)
    CHUNK(5,  p0, 16)
    CHUNK(6,  p1, 16)
    CHUNK(7,  p2, 16)
    CHUNK(8,  p3, 12)
    CHUNK(9,  p4, 8)
    CHUNK(10, p0, 4)
    CHUNK(11, p1, 0)

    __syncthreads();                                    // all waves done reading B

    // ---- stage Q/K/VT to LDS (C/D layout: col=l15, row=lg*4+j) ----
#pragma unroll
    for (int m = 0; m < 2; ++m) {
#pragma unroll
        for (int n = 0; n < 12; ++n) {
            int col = n * 16 + l15;
#pragma unroll
            for (int j = 0; j < 4; ++j) {
                int t = wid * 32 + m * 16 + lg * 4 + j;
                unsigned short hv = f2bf(acc[m][n][j]);
                if (col < 64)
                    *reinterpret_cast<unsigned short*>(smem + QOFF + (t * 72 + col) * 2) = hv;
                else if (col < 128)
                    *reinterpret_cast<unsigned short*>(smem + KOFF + (t * 72 + (col - 64)) * 2) = hv;
                else
                    *reinterpret_cast<unsigned short*>(smem + VTOFF + ((col - 128) * 264 + t) * 2) = hv;
            }
        }
    }
    __syncthreads();

    // ---------------- phase 2: causal attention, 8 waves x 32-row strips ------------
    char* Pw = smem + POFF + wid * 4608;               // per-wave P[32][72]
    const int r0 = wid * 32;
    if (wid < 2)      attn_strip<1>(smem, Pw, ob, r0, l15, lg);
    else if (wid < 4) attn_strip<2>(smem, Pw, ob, r0, l15, lg);
    else if (wid < 6) attn_strip<3>(smem, Pw, ob, r0, l15, lg);
    else              attn_strip<4>(smem, Pw, ob, r0, l15, lg);
}

extern "C" void kernel_launch(void* const* d_in, const int* in_sizes, int n_in,
                              void* d_out, int out_size, void* d_ws, size_t ws_size,
                              hipStream_t stream) {
    const float* x  = (const float*)d_in[0];
    const float* Wq = (const float*)d_in[1];
    const float* Wk = (const float*)d_in[2];
    const float* Wv = (const float*)d_in[3];
    float* out = (float*)d_out;

    unsigned short* Wt2 = (unsigned short*)d_ws;   // [12][4][192][8] bf16 = 147456 B

    wprep<<<288, 256, 0, stream>>>(Wq, Wk, Wv, Wt2);
    fused<<<256, 512, 0, stream>>>(x, Wt2, out);
}

// Round 11
// 38.303 us; speedup vs baseline: 1.8026x; 1.0309x over previous
//
#include <hip/hip_runtime.h>
#include <hip/hip_bf16.h>

typedef __attribute__((ext_vector_type(8))) short bf16x8;
typedef __attribute__((ext_vector_type(4))) float f32x4;

__device__ __forceinline__ unsigned short f2bf(float f) {
    union { float f; unsigned int u; } v; v.f = f;
    unsigned int u = v.u;
    unsigned int r = u + 0x7FFFu + ((u >> 16) & 1u);   // RNE
    return (unsigned short)(r >> 16);
}

__device__ __forceinline__ unsigned int cvtpk(float lo, float hi) {
    unsigned int r;
    asm("v_cvt_pk_bf16_f32 %0, %1, %2" : "=v"(r) : "v"(lo), "v"(hi));
    return r;
}

__device__ __forceinline__ float frcp(float x) {
    float r;
    asm("v_rcp_f32 %0, %1" : "=v"(r) : "v"(x));
    return r;
}

#define GLDS16(gsrc, ldst)                                                          \
    __builtin_amdgcn_global_load_lds(                                               \
        (const __attribute__((address_space(1))) unsigned int*)(gsrc),              \
        (__attribute__((address_space(3))) unsigned int*)(ldst), 16, 0, 0)

// ---------------- kernel 0: W -> Wt2 [c=12][kc2=4][col=192][8] bf16 ----------------
__global__ __launch_bounds__(256) void wprep(const float* __restrict__ Wq,
                                             const float* __restrict__ Wk,
                                             const float* __restrict__ Wv,
                                             unsigned short* __restrict__ Wt2) {
    int idx = blockIdx.x * 256 + threadIdx.x;          // 3*64*384 = 73728
    if (idx >= 73728) return;
    int w   = idx / 24576;
    int rem = idx % 24576;
    int n = rem / 384, k = rem % 384;
    const float* W = (w == 0) ? Wq : ((w == 1) ? Wk : Wv);
    int col = w * 64 + n;
    Wt2[(size_t)(k >> 5) * 6144 + ((k >> 3) & 3) * 1536 + col * 8 + (k & 7)] = f2bf(W[k * 64 + n]);
}

#define QOFF  0
#define KOFF  36864
#define VTOFF 73728
#define POFF  107520

// ---------------- phase 2 helper: 16-row strip, NT causal 64-col tiles --------------
// Single-pass softmax (S in regs), mask only on last tile, rcp-normalize,
// out stores coalesced via padded f32 LDS tile (reuses Pw region).
template<int NT>
__device__ __forceinline__ void attn_strip16(char* smem, char* Pw, float* __restrict__ ob,
                                             int r0, int lane) {
    const int l15 = lane & 15, lg = lane >> 4;
    const float scale = 0.05103103630798287f;          // 384^-0.5

    bf16x8 aq[2];
#pragma unroll
    for (int kk = 0; kk < 2; ++kk)
        aq[kk] = *reinterpret_cast<const bf16x8*>(smem + QOFF + ((r0 + l15) * 72 + kk * 32 + lg * 8) * 2);

    f32x4 s[NT][4] = {};
#pragma unroll
    for (int jt = 0; jt < NT; ++jt)
#pragma unroll
        for (int kk = 0; kk < 2; ++kk) {
            bf16x8 bk[4];
#pragma unroll
            for (int n = 0; n < 4; ++n)
                bk[n] = *reinterpret_cast<const bf16x8*>(smem + KOFF + ((jt * 64 + n * 16 + l15) * 72 + kk * 32 + lg * 8) * 2);
#pragma unroll
            for (int n = 0; n < 4; ++n)
                s[jt][n] = __builtin_amdgcn_mfma_f32_16x16x32_bf16(aq[kk], bk[n], s[jt][n], 0, 0, 0);
        }

    // scale + (last-tile) causal mask + row-max
    float M[4];
#pragma unroll
    for (int j = 0; j < 4; ++j) M[j] = -1e30f;
#pragma unroll
    for (int jt = 0; jt < NT; ++jt)
#pragma unroll
        for (int n = 0; n < 4; ++n) {
            int colg = jt * 64 + n * 16 + l15;
#pragma unroll
            for (int j = 0; j < 4; ++j) {
                float v = s[jt][n][j] * scale;
                if (jt == NT - 1) {                     // earlier tiles statically valid
                    int rowg = r0 + lg * 4 + j;
                    if (colg > rowg) v = -1e30f;
                }
                s[jt][n][j] = v;
                M[j] = fmaxf(M[j], v);
            }
        }
#pragma unroll
    for (int j = 0; j < 4; ++j) {
        float v = M[j];
        v = fmaxf(v, __shfl_xor(v, 1));
        v = fmaxf(v, __shfl_xor(v, 2));
        v = fmaxf(v, __shfl_xor(v, 4));
        v = fmaxf(v, __shfl_xor(v, 8));
        M[j] = v;
    }
    // exp + row-sum
    float L[4] = {};
#pragma unroll
    for (int jt = 0; jt < NT; ++jt)
#pragma unroll
        for (int n = 0; n < 4; ++n)
#pragma unroll
            for (int j = 0; j < 4; ++j) {
                float p = __expf(s[jt][n][j] - M[j]);
                s[jt][n][j] = p;
                L[j] += p;
            }
    float rL[4];
#pragma unroll
    for (int j = 0; j < 4; ++j) {
        float v = L[j];
        v += __shfl_xor(v, 1);
        v += __shfl_xor(v, 2);
        v += __shfl_xor(v, 4);
        v += __shfl_xor(v, 8);
        rL[j] = frcp(v);
    }
    // per-tile: P -> LDS, PV accumulate
    f32x4 o[4] = {};
#pragma unroll
    for (int jt = 0; jt < NT; ++jt) {
#pragma unroll
        for (int n = 0; n < 4; ++n)
#pragma unroll
            for (int j = 0; j < 4; ++j)
                *reinterpret_cast<unsigned short*>(Pw + ((lg * 4 + j) * 72 + n * 16 + l15) * 2) = f2bf(s[jt][n][j]);
        asm volatile("s_waitcnt lgkmcnt(0)" ::: "memory");   // wave-internal LDS RAW fence
#pragma unroll
        for (int kk = 0; kk < 2; ++kk) {
            bf16x8 ap, bv[4];
            ap = *reinterpret_cast<const bf16x8*>(Pw + (l15 * 72 + kk * 32 + lg * 8) * 2);
#pragma unroll
            for (int n = 0; n < 4; ++n)
                bv[n] = *reinterpret_cast<const bf16x8*>(smem + VTOFF + ((n * 16 + l15) * 264 + jt * 64 + kk * 32 + lg * 8) * 2);
#pragma unroll
            for (int n = 0; n < 4; ++n)
                o[n] = __builtin_amdgcn_mfma_f32_16x16x32_bf16(ap, bv[n], o[n], 0, 0, 0);
        }
    }
    // coalesced epilogue: o -> padded f32 LDS tile [16][68] (reuses Pw) -> dwordx4
    float* tf = reinterpret_cast<float*>(Pw);
#pragma unroll
    for (int n = 0; n < 4; ++n)
#pragma unroll
        for (int j = 0; j < 4; ++j)
            tf[(lg * 4 + j) * 68 + n * 16 + l15] = o[n][j] * rL[j];
    asm volatile("s_waitcnt lgkmcnt(0)" ::: "memory");       // writes landed (in-order per wave)
#pragma unroll
    for (int i = 0; i < 4; ++i) {
        int row = i * 4 + lg;
        float4 vv = *reinterpret_cast<const float4*>(&tf[row * 68 + l15 * 4]);
        *reinterpret_cast<float4*>(ob + (size_t)(r0 + row) * 64 + l15 * 4) = vv;
    }
}

// ---------------- fused kernel: one block per batch, 512 threads / 8 waves ----------
__global__ __launch_bounds__(512, 1) void fused(const float* __restrict__ x,
                                                const unsigned short* __restrict__ Wt2,
                                                float* __restrict__ out) {
    __shared__ __align__(16) char smem[147456];

    const int b = blockIdx.x;
    const int tid = threadIdx.x, lane = tid & 63, wid = tid >> 6;   // wid 0..7
    const int l15 = lane & 15, lg = lane >> 4;
    const float* xb = x + (size_t)b * 98304;
    float* ob = out + (size_t)b * 16384;

    // ---- stage ALL of B once: 18 glds/wave, linear ----
#pragma unroll
    for (int i = 0; i < 18; ++i) {
        int n = wid * 18 + i;
        GLDS16(Wt2 + (size_t)n * 512 + lane * 8, smem + n * 1024);
    }

    // ---- x pointer: wave w rows w*32 + {0,16} + l15, k-offset lg*8 ----
    const float* xw = xb + (size_t)(wid * 32 + l15) * 384 + lg * 8;

    float4 p0[4], p1[4], p2[4], p3[4], p4[4];
#define XLOAD(P, C)                                                                 \
    P[0] = *reinterpret_cast<const float4*>(xw + (C) * 32);                         \
    P[1] = *reinterpret_cast<const float4*>(xw + (C) * 32 + 4);                     \
    P[2] = *reinterpret_cast<const float4*>(xw + 6144 + (C) * 32);                  \
    P[3] = *reinterpret_cast<const float4*>(xw + 6144 + (C) * 32 + 4);
    XLOAD(p0, 0)
    XLOAD(p1, 1)
    XLOAD(p2, 2)
    XLOAD(p3, 3)
    XLOAD(p4, 4)
    __builtin_amdgcn_sched_barrier(0);
    asm volatile("s_waitcnt vmcnt(20)" ::: "memory");   // 18 B glds landed; x 0..4 in flight
    __builtin_amdgcn_s_barrier();                       // B visible to all waves

    f32x4 acc[2][12] = {};

#define CHUNK(C, P, WAITN)                                                          \
    asm volatile("s_waitcnt vmcnt(" #WAITN ")" ::: "memory");                       \
    __builtin_amdgcn_sched_barrier(0);                                              \
    {                                                                               \
        union { unsigned int u[4]; bf16x8 v; } cv0, cv1;                            \
        cv0.u[0] = cvtpk(P[0].x, P[0].y); cv0.u[1] = cvtpk(P[0].z, P[0].w);         \
        cv0.u[2] = cvtpk(P[1].x, P[1].y); cv0.u[3] = cvtpk(P[1].z, P[1].w);         \
        cv1.u[0] = cvtpk(P[2].x, P[2].y); cv1.u[1] = cvtpk(P[2].z, P[2].w);         \
        cv1.u[2] = cvtpk(P[3].x, P[3].y); cv1.u[3] = cvtpk(P[3].z, P[3].w);         \
        bf16x8 a0 = cv0.v, a1 = cv1.v;                                              \
        if ((C) + 5 < 12) { XLOAD(P, (C) + 5) }                                     \
        __builtin_amdgcn_sched_barrier(0);                                          \
        const char* bs = smem + (C) * 12288 + lg * 3072 + l15 * 16;                 \
        _Pragma("unroll")                                                           \
        for (int n = 0; n < 12; ++n) {                                              \
            bf16x8 bf = *reinterpret_cast<const bf16x8*>(bs + n * 256);             \
            acc[0][n] = __builtin_amdgcn_mfma_f32_16x16x32_bf16(a0, bf, acc[0][n], 0, 0, 0); \
            acc[1][n] = __builtin_amdgcn_mfma_f32_16x16x32_bf16(a1, bf, acc[1][n], 0, 0, 0); \
        }                                                                           \
    }

    CHUNK(0,  p0, 16)
    CHUNK(1,  p1, 16)
    CHUNK(2,  p2, 16)
    CHUNK(3,  p3, 16)
    CHUNK(4,  p4, 16)
    CHUNK(5,  p0, 16)
    CHUNK(6,  p1, 16)
    CHUNK(7,  p2, 16)
    CHUNK(8,  p3, 12)
    CHUNK(9,  p4, 8)
    CHUNK(10, p0, 4)
    CHUNK(11, p1, 0)

    __syncthreads();                                    // all waves done reading B

    // ---- stage Q/K/VT to LDS (C/D layout: col=l15, row=lg*4+j) ----
#pragma unroll
    for (int m = 0; m < 2; ++m) {
        const int t0 = wid * 32 + m * 16 + lg * 4;
#pragma unroll
        for (int n = 0; n < 4; ++n) {                   // Q cols 0..63
            int col = n * 16 + l15;
#pragma unroll
            for (int j = 0; j < 4; ++j)
                *reinterpret_cast<unsigned short*>(smem + QOFF + ((t0 + j) * 72 + col) * 2) = f2bf(acc[m][n][j]);
        }
#pragma unroll
        for (int n = 4; n < 8; ++n) {                   // K cols 0..63
            int col = (n - 4) * 16 + l15;
#pragma unroll
            for (int j = 0; j < 4; ++j)
                *reinterpret_cast<unsigned short*>(smem + KOFF + ((t0 + j) * 72 + col) * 2) = f2bf(acc[m][n][j]);
        }
#pragma unroll
        for (int n = 8; n < 12; ++n) {                  // VT[h][t], t contiguous in j -> b64
            int h = (n - 8) * 16 + l15;
            ushort4 h4;
            h4.x = f2bf(acc[m][n][0]); h4.y = f2bf(acc[m][n][1]);
            h4.z = f2bf(acc[m][n][2]); h4.w = f2bf(acc[m][n][3]);
            *reinterpret_cast<ushort4*>(smem + VTOFF + (h * 264 + t0) * 2) = h4;
        }
    }
    __syncthreads();

    // ---------------- phase 2: balanced — wave w owns strips {w, 15-w} --------------
    char* Pw = smem + POFF + wid * 4608;                // P[16][72] bf16 / f32 tile [16][68]
    if (wid < 4) {
        attn_strip16<1>(smem, Pw, ob, wid * 16, lane);
        attn_strip16<4>(smem, Pw, ob, (15 - wid) * 16, lane);
    } else {
        attn_strip16<2>(smem, Pw, ob, wid * 16, lane);
        attn_strip16<3>(smem, Pw, ob, (15 - wid) * 16, lane);
    }
}

extern "C" void kernel_launch(void* const* d_in, const int* in_sizes, int n_in,
                              void* d_out, int out_size, void* d_ws, size_t ws_size,
                              hipStream_t stream) {
    const float* x  = (const float*)d_in[0];
    const float* Wq = (const float*)d_in[1];
    const float* Wk = (const float*)d_in[2];
    const float* Wv = (const float*)d_in[3];
    float* out = (float*)d_out;

    unsigned short* Wt2 = (unsigned short*)d_ws;   // [12][4][192][8] bf16 = 147456 B

    wprep<<<288, 256, 0, stream>>>(Wq, Wk, Wv, Wt2);
    fused<<<256, 512, 0, stream>>>(x, Wt2, out);
}